// Round 4
// baseline (14284.659 us; speedup 1.0000x reference)
//
#include <hip/hip_runtime.h>
#include <hip/hip_bf16.h>
#include <stdint.h>

// LSTM scan R4: slot-vector barrier (no RMW, no flag hop).
// T=2048, B=64, DIN=H=512. Grid = 4 row-groups x 16 col-WGs = 64 WGs x 256 thr.
// Group g owns batch rows [16g,16g+16); WG (g,wc) owns h-cols [32wc,32wc+32).
// Weights in registers as MFMA B-frags. Waves 0,1: Wx K-halves (no barrier
// dep); waves 2,3: Wh K-halves.
//
// Coherence protocol (LLC-direct, validated in R3; no wbl2/inv anywhere):
//   h stores: packed 2xbf16 agent-scope RELAXED atomic dword stores (sc1).
//   h loads:  agent-scope RELAXED atomic dwordx2 (sc1, always LLC-fresh).
// Barrier (new in R4): per-group 16-dword slot vector in ONE 64B LLC line.
//   produce: __syncthreads (vmcnt(0) acks h-stores at LLC) then tid0
//            relax-stores epoch t+1 into slots[wc] -- 16 parallel plain
//            writes, no RMW ownership chain (R3's fetch_add serialized 16
//            LLC RMWs + needed an extra flag-line hop).
//   consume: lane reads slots[lane&15] (one coalesced transaction/wave),
//            exit on __all(v >= t); no s_sleep (poll self-throttles at
//            ~1 LLC round trip per iteration).

#define TSTEPS 2048
#define BATCH  64
#define DINK   512
#define HHH    512
#define GB     4
#define GC     16
#define ROWS   16
#define NTHR   256

typedef __attribute__((ext_vector_type(8))) short  short8;
typedef __attribute__((ext_vector_type(4))) float  float4v;

static __device__ __forceinline__ unsigned short f2bf(float f) {
    union { float f; unsigned u; } v; v.f = f;
    unsigned u = v.u + 0x7FFFu + ((v.u >> 16) & 1u);   // RNE
    return (unsigned short)(u >> 16);
}
static __device__ __forceinline__ float sigm(float x) {
    return 1.0f / (1.0f + __expf(-x));
}
static __device__ __forceinline__ float tanh_fast(float x) {
    return 2.0f / (1.0f + __expf(-2.0f * x)) - 1.0f;
}

__global__ __launch_bounds__(NTHR, 1) void lstm_scan(
    const float* __restrict__ X,   // [T][64][512]
    const float* __restrict__ Wx,  // [512][2048]
    const float* __restrict__ bx,  // [2048]
    const float* __restrict__ Wh,  // [512][2048]
    const float* __restrict__ bh,  // [2048]
    float* out,                    // [2][64][512]
    unsigned short* hbuf,          // 2 x [64][512] bf16 (zeroed)
    unsigned* sync)                // group g: slots = sync + g*64, 16 dwords (one line)
{
    __shared__ float P[4][ROWS][132];   // per-wave K-partials
    __shared__ float cst[ROWS][33];
    __shared__ float hsum[ROWS][33];
    __shared__ float csum[ROWS][33];
    __shared__ float biasLds[128];

    const int tid  = threadIdx.x;
    const int wv   = tid >> 6;
    const int lane = tid & 63;
    const int l15  = lane & 15;
    const int quad = lane >> 4;
    const int g    = blockIdx.x >> 4;   // row group 0..3
    const int wc   = blockIdx.x & 15;   // col-WG 0..15
    const int rb   = g * ROWS;          // first batch row of group
    const int jbase = wc * 32;          // first h-col of WG

    unsigned* slots = sync + g * 64;    // 16 used dwords, one 64B line

    // ---- preload B fragments (weights, bf16) into registers ----
    const float* Wsrc = (wv < 2) ? Wx : Wh;
    const int k0 = (wv & 1) * 256;
    short8 bfrag[8][8];
    #pragma unroll
    for (int kc = 0; kc < 8; ++kc) {
        #pragma unroll
        for (int nt = 0; nt < 8; ++nt) {
            const int c    = nt * 16 + l15;                  // 0..127
            const int gcol = (c >> 5) * HHH + jbase + (c & 31);
            const int kl   = k0 + kc * 32 + quad * 8;
            short8 tmp;
            #pragma unroll
            for (int j = 0; j < 8; ++j)
                tmp[j] = (short)f2bf(Wsrc[(size_t)(kl + j) * 2048 + gcol]);
            bfrag[kc][nt] = tmp;
        }
    }
    if (tid < 128) {
        const int gcol = (tid >> 5) * HHH + jbase + (tid & 31);
        biasLds[tid] = bx[gcol] + bh[gcol];
    }
    for (int i = tid; i < ROWS * 33; i += NTHR) {
        (&cst[0][0])[i] = 0.f; (&hsum[0][0])[i] = 0.f; (&csum[0][0])[i] = 0.f;
    }
    __syncthreads();

    const int r_ew  = tid >> 4;          // 0..15 (row in group)
    const int jj_ew = (tid & 15) * 2;    // 0,2,..,30 (adjacent pair of h-cols)

    for (int t = 0; t < TSTEPS; ++t) {
        const unsigned short* hR = hbuf + ((t + 1) & 1) * (BATCH * HHH);
        unsigned short*       hW = hbuf + (t & 1)       * (BATCH * HHH);

        float4v acc[8];
        #pragma unroll
        for (int nt = 0; nt < 8; ++nt) acc[nt] = (float4v){0.f, 0.f, 0.f, 0.f};

        if (wv < 2) {
            // x waves: independent of the barrier; overlap with h-wave wait
            const float* xbase = X + (size_t)t * (BATCH * DINK) + (size_t)(rb + l15) * DINK;
            #pragma unroll
            for (int kc = 0; kc < 8; ++kc) {
                const int kg = k0 + kc * 32 + quad * 8;
                const float4v* p = (const float4v*)(xbase + kg);
                float4v x0 = p[0], x1 = p[1];
                short8 a;
                a[0] = (short)f2bf(x0[0]); a[1] = (short)f2bf(x0[1]);
                a[2] = (short)f2bf(x0[2]); a[3] = (short)f2bf(x0[3]);
                a[4] = (short)f2bf(x1[0]); a[5] = (short)f2bf(x1[1]);
                a[6] = (short)f2bf(x1[2]); a[7] = (short)f2bf(x1[3]);
                #pragma unroll
                for (int nt = 0; nt < 8; ++nt)
                    acc[nt] = __builtin_amdgcn_mfma_f32_16x16x32_bf16(
                        a, bfrag[kc][nt], acc[nt], 0, 0, 0);
            }
        } else {
            if (t > 0) {
                // poll slot vector: 16 dwords, one line, one transaction/wave
                for (;;) {
                    unsigned v = __hip_atomic_load(slots + l15, __ATOMIC_RELAXED,
                                                   __HIP_MEMORY_SCOPE_AGENT);
                    if (__all((int)(v >= (unsigned)t))) break;
                }
                __builtin_amdgcn_fence(__ATOMIC_ACQUIRE, "workgroup");  // order only
            }
            const int hc0 = (wv - 2) * 256;
            #pragma unroll
            for (int kc = 0; kc < 8; ++kc) {
                const int hc = hc0 + kc * 32 + quad * 8;
                const unsigned long long* hp =
                    (const unsigned long long*)(hR + (size_t)(rb + l15) * HHH + hc);
                unsigned long long lo = __hip_atomic_load(hp,     __ATOMIC_RELAXED, __HIP_MEMORY_SCOPE_AGENT);
                unsigned long long hi = __hip_atomic_load(hp + 1, __ATOMIC_RELAXED, __HIP_MEMORY_SCOPE_AGENT);
                union { unsigned long long q[2]; short8 s; } u;
                u.q[0] = lo; u.q[1] = hi;
                #pragma unroll
                for (int nt = 0; nt < 8; ++nt)
                    acc[nt] = __builtin_amdgcn_mfma_f32_16x16x32_bf16(
                        u.s, bfrag[kc][nt], acc[nt], 0, 0, 0);
            }
        }

        // K-partials to LDS (C layout: row = quad*4+r, col = nt*16+l15)
        #pragma unroll
        for (int nt = 0; nt < 8; ++nt) {
            const int col = nt * 16 + l15;
            #pragma unroll
            for (int r = 0; r < 4; ++r)
                P[wv][quad * 4 + r][col] = acc[nt][r];
        }
        __syncthreads();

        // elementwise: thread -> (row r_ew, h-cols jj_ew, jj_ew+1)
        {
            float h2[2];
            #pragma unroll
            for (int e = 0; e < 2; ++e) {
                const int jj = jj_ew + e;
                const int r  = r_ew;
                float gi = biasLds[jj]      + P[0][r][jj]      + P[1][r][jj]      + P[2][r][jj]      + P[3][r][jj];
                float gf = biasLds[32 + jj] + P[0][r][32 + jj] + P[1][r][32 + jj] + P[2][r][32 + jj] + P[3][r][32 + jj];
                float go = biasLds[64 + jj] + P[0][r][64 + jj] + P[1][r][64 + jj] + P[2][r][64 + jj] + P[3][r][64 + jj];
                float gz = biasLds[96 + jj] + P[0][r][96 + jj] + P[1][r][96 + jj] + P[2][r][96 + jj] + P[3][r][96 + jj];
                const float c_old = cst[r][jj];
                const float cn = sigm(gi) * tanh_fast(gz) + sigm(gf) * c_old;
                const float hn = sigm(go) * tanh_fast(cn);
                cst[r][jj]  = cn;
                csum[r][jj] += cn;
                hsum[r][jj] += hn;
                h2[e] = hn;
            }
            const unsigned pk = (unsigned)f2bf(h2[0]) | ((unsigned)f2bf(h2[1]) << 16);
            unsigned* dst = (unsigned*)(hW + (size_t)(rb + r_ew) * HHH + jbase + jj_ew);
            __hip_atomic_store(dst, pk, __ATOMIC_RELAXED, __HIP_MEMORY_SCOPE_AGENT);  // sc1 -> LLC
        }
        __syncthreads();   // vmcnt(0): all sc1 h-stores of this WG acked at LLC
        if (tid == 0)
            __hip_atomic_store(slots + wc, (unsigned)(t + 1), __ATOMIC_RELAXED,
                               __HIP_MEMORY_SCOPE_AGENT);   // parallel slot write, no RMW
    }

    // global final barrier (covers the d_out-fallback aliasing case): every
    // wave checks all 4 groups x 16 slots via its 64 lanes, then WG-syncs.
    {
        unsigned* base = sync + (lane & 3) * 64 + ((lane >> 2) & 15);
        for (;;) {
            unsigned v = __hip_atomic_load(base, __ATOMIC_RELAXED, __HIP_MEMORY_SCOPE_AGENT);
            if (__all((int)(v >= (unsigned)TSTEPS))) break;
        }
    }
    __syncthreads();

    const float invT = 1.0f / (float)TSTEPS;
    {
        const int b = rb + r_ew;
        const size_t o0 = (size_t)b * HHH + jbase + jj_ew;
        out[o0]                              = hsum[r_ew][jj_ew] * invT;
        out[o0 + 1]                          = hsum[r_ew][jj_ew + 1] * invT;
        out[(size_t)(BATCH * HHH) + o0]      = csum[r_ew][jj_ew] * invT;
        out[(size_t)(BATCH * HHH) + o0 + 1]  = csum[r_ew][jj_ew + 1] * invT;
    }
}

extern "C" void kernel_launch(void* const* d_in, const int* in_sizes, int n_in,
                              void* d_out, int out_size, void* d_ws, size_t ws_size,
                              hipStream_t stream) {
    (void)in_sizes; (void)n_in; (void)out_size;
    const float* X  = (const float*)d_in[0];
    const float* Wx = (const float*)d_in[1];
    const float* bx = (const float*)d_in[2];
    const float* Wh = (const float*)d_in[3];
    const float* bh = (const float*)d_in[4];
    float* out = (float*)d_out;

    const size_t HBUF_BYTES = (size_t)2 * BATCH * HHH * 2;   // 128 KiB
    const size_t SYNC_BYTES = 4096;                          // 4 groups x 256B lines
    char* scratch = (ws_size >= HBUF_BYTES + SYNC_BYTES) ? (char*)d_ws : (char*)d_out;
    unsigned short* hbuf = (unsigned short*)scratch;
    unsigned* sync = (unsigned*)(scratch + HBUF_BYTES);

    hipMemsetAsync(scratch, 0, HBUF_BYTES + SYNC_BYTES, stream);
    lstm_scan<<<GB * GC, NTHR, 0, stream>>>(X, Wx, bx, Wh, bh, out, hbuf, sync);
}

// Round 5
// 9436.936 us; speedup vs baseline: 1.5137x; 1.5137x over previous
//
#include <hip/hip_runtime.h>
#include <hip/hip_bf16.h>
#include <stdint.h>

// LSTM scan R5: batched VMEM via inline asm + per-wave early publish.
// T=2048, B=64, DIN=H=512. Grid = 4 row-groups x 16 col-WGs = 64 WGs x 256 thr.
// Group g owns batch rows [16g,16g+16); WG (g,wc) owns h-cols [32wc,32wc+32).
// Weights in registers as MFMA B-frags. Waves 0,1: Wx K-halves (no barrier
// dep); waves 2,3: Wh K-halves.
//
// R4 post-mortem: barrier restructure was neutral -> bottleneck is VMEM
// serialization. Atomic 8B h-loads were not batched by the compiler (16
// serial LLC round trips ~5us); x HBM loads likewise under 256-VGPR bfrag
// pressure (~6.4us, matching the measured 6.9us/step). R5 issues all loads
// back-to-back via asm with offset immediates and waits ONCE:
//   h: 8x global_load_dwordx4 sc0 sc1 (LLC-fresh) + s_waitcnt vmcnt(0)
//   x: 16x global_load_dwordx4 + vmcnt(8)/vmcnt(0) two-phase consume
// Publish: per-WAVE (not per-WG): each wave drains its own h-stores
// (s_waitcnt vmcnt(0)) and lane0 stores epoch into slots[wc*4+wv]; consumers
// poll the 64-slot line (one read per lane, __all exit). Removes the second
// __syncthreads from the publish critical path.

#define TSTEPS 2048
#define BATCH  64
#define DINK   512
#define HHH    512
#define GB     4
#define GC     16
#define ROWS   16
#define NTHR   256

typedef __attribute__((ext_vector_type(8))) short  short8;
typedef __attribute__((ext_vector_type(4))) float  float4v;
typedef __attribute__((ext_vector_type(4))) int    int4v;

static __device__ __forceinline__ unsigned short f2bf(float f) {
    union { float f; unsigned u; } v; v.f = f;
    unsigned u = v.u + 0x7FFFu + ((v.u >> 16) & 1u);   // RNE
    return (unsigned short)(u >> 16);
}
static __device__ __forceinline__ float sigm(float x) {
    return 1.0f / (1.0f + __expf(-x));
}
static __device__ __forceinline__ float tanh_fast(float x) {
    return 2.0f / (1.0f + __expf(-2.0f * x)) - 1.0f;
}

__global__ __launch_bounds__(NTHR, 1) void lstm_scan(
    const float* __restrict__ X,   // [T][64][512]
    const float* __restrict__ Wx,  // [512][2048]
    const float* __restrict__ bx,  // [2048]
    const float* __restrict__ Wh,  // [512][2048]
    const float* __restrict__ bh,  // [2048]
    float* out,                    // [2][64][512]
    unsigned short* hbuf,          // 2 x [64][512] bf16 (zeroed)
    unsigned* sync)                // group g: 64 slots at sync + g*64 (256B)
{
    __shared__ float P[4][ROWS][132];
    __shared__ float cst[ROWS][33];
    __shared__ float hsum[ROWS][33];
    __shared__ float csum[ROWS][33];
    __shared__ float biasLds[128];

    const int tid  = threadIdx.x;
    const int wv   = tid >> 6;
    const int lane = tid & 63;
    const int l15  = lane & 15;
    const int quad = lane >> 4;
    const int g    = blockIdx.x >> 4;   // row group 0..3
    const int wc   = blockIdx.x & 15;   // col-WG 0..15
    const int rb   = g * ROWS;
    const int jbase = wc * 32;

    unsigned* slots = sync + g * 64;    // 64 dwords: slot per (wc,wv)

    // ---- preload B fragments (weights, bf16) into registers ----
    const float* Wsrc = (wv < 2) ? Wx : Wh;
    const int k0 = (wv & 1) * 256;
    short8 bfrag[8][8];
    #pragma unroll
    for (int kc = 0; kc < 8; ++kc) {
        #pragma unroll
        for (int nt = 0; nt < 8; ++nt) {
            const int c    = nt * 16 + l15;
            const int gcol = (c >> 5) * HHH + jbase + (c & 31);
            const int kl   = k0 + kc * 32 + quad * 8;
            short8 tmp;
            #pragma unroll
            for (int j = 0; j < 8; ++j)
                tmp[j] = (short)f2bf(Wsrc[(size_t)(kl + j) * 2048 + gcol]);
            bfrag[kc][nt] = tmp;
        }
    }
    if (tid < 128) {
        const int gcol = (tid >> 5) * HHH + jbase + (tid & 31);
        biasLds[tid] = bx[gcol] + bh[gcol];
    }
    for (int i = tid; i < ROWS * 33; i += NTHR) {
        (&cst[0][0])[i] = 0.f; (&hsum[0][0])[i] = 0.f; (&csum[0][0])[i] = 0.f;
    }
    __syncthreads();

    const int r_ew  = tid >> 4;          // 0..15 (row in group)
    const int jj_ew = (tid & 15) * 2;    // 0,2,..,30

    for (int t = 0; t < TSTEPS; ++t) {
        const unsigned short* hR = hbuf + ((t + 1) & 1) * (BATCH * HHH);
        unsigned short*       hW = hbuf + (t & 1)       * (BATCH * HHH);

        float4v acc[8];
        #pragma unroll
        for (int nt = 0; nt < 8; ++nt) acc[nt] = (float4v){0.f, 0.f, 0.f, 0.f};

        if (wv < 2) {
            // ---- x path: 16 loads issued back-to-back, two-phase consume ----
            const float* xrow = X + (size_t)t * (BATCH * DINK)
                                  + (size_t)(rb + l15) * DINK + k0 + quad * 8;
            int4v xv[16];
            // kc stride = 32 floats = 128 B; pair at +0 / +16 B
            #define XLOAD(i, OFF) asm volatile( \
                "global_load_dwordx4 %0, %1, off offset:" OFF \
                : "=v"(xv[i]) : "v"(xrow))
            XLOAD( 0, "0");    XLOAD( 1, "16");
            XLOAD( 2, "128");  XLOAD( 3, "144");
            XLOAD( 4, "256");  XLOAD( 5, "272");
            XLOAD( 6, "384");  XLOAD( 7, "400");
            XLOAD( 8, "512");  XLOAD( 9, "528");
            XLOAD(10, "640");  XLOAD(11, "656");
            XLOAD(12, "768");  XLOAD(13, "784");
            XLOAD(14, "896");  XLOAD(15, "912");
            #undef XLOAD
            asm volatile("s_waitcnt vmcnt(8)"
                : "+v"(xv[0]), "+v"(xv[1]), "+v"(xv[2]), "+v"(xv[3]),
                  "+v"(xv[4]), "+v"(xv[5]), "+v"(xv[6]), "+v"(xv[7]));
            #pragma unroll
            for (int kc = 0; kc < 4; ++kc) {
                union { int4v i; float4v f; } a0, a1;
                a0.i = xv[2 * kc]; a1.i = xv[2 * kc + 1];
                short8 av;
                av[0] = (short)f2bf(a0.f[0]); av[1] = (short)f2bf(a0.f[1]);
                av[2] = (short)f2bf(a0.f[2]); av[3] = (short)f2bf(a0.f[3]);
                av[4] = (short)f2bf(a1.f[0]); av[5] = (short)f2bf(a1.f[1]);
                av[6] = (short)f2bf(a1.f[2]); av[7] = (short)f2bf(a1.f[3]);
                #pragma unroll
                for (int nt = 0; nt < 8; ++nt)
                    acc[nt] = __builtin_amdgcn_mfma_f32_16x16x32_bf16(
                        av, bfrag[kc][nt], acc[nt], 0, 0, 0);
            }
            asm volatile("s_waitcnt vmcnt(0)"
                : "+v"(xv[8]),  "+v"(xv[9]),  "+v"(xv[10]), "+v"(xv[11]),
                  "+v"(xv[12]), "+v"(xv[13]), "+v"(xv[14]), "+v"(xv[15]));
            #pragma unroll
            for (int kc = 4; kc < 8; ++kc) {
                union { int4v i; float4v f; } a0, a1;
                a0.i = xv[2 * kc]; a1.i = xv[2 * kc + 1];
                short8 av;
                av[0] = (short)f2bf(a0.f[0]); av[1] = (short)f2bf(a0.f[1]);
                av[2] = (short)f2bf(a0.f[2]); av[3] = (short)f2bf(a0.f[3]);
                av[4] = (short)f2bf(a1.f[0]); av[5] = (short)f2bf(a1.f[1]);
                av[6] = (short)f2bf(a1.f[2]); av[7] = (short)f2bf(a1.f[3]);
                #pragma unroll
                for (int nt = 0; nt < 8; ++nt)
                    acc[nt] = __builtin_amdgcn_mfma_f32_16x16x32_bf16(
                        av, bfrag[kc][nt], acc[nt], 0, 0, 0);
            }
        } else {
            // ---- h path: poll 64-slot line, then 8 LLC loads in one batch ----
            if (t > 0) {
                for (;;) {
                    unsigned v = __hip_atomic_load(slots + lane, __ATOMIC_RELAXED,
                                                   __HIP_MEMORY_SCOPE_AGENT);
                    if (__all((int)(v >= (unsigned)t))) break;
                }
                __builtin_amdgcn_fence(__ATOMIC_ACQUIRE, "workgroup");  // order only
            }
            const int hc0 = (wv - 2) * 256;
            const unsigned short* hrow = hR + (size_t)(rb + l15) * HHH + hc0 + quad * 8;
            int4v hv[8];
            // kc stride = 32 bf16 = 64 B
            #define HLOAD(i, OFF) asm volatile( \
                "global_load_dwordx4 %0, %1, off offset:" OFF " sc0 sc1" \
                : "=v"(hv[i]) : "v"(hrow))
            HLOAD(0, "0");   HLOAD(1, "64");  HLOAD(2, "128"); HLOAD(3, "192");
            HLOAD(4, "256"); HLOAD(5, "320"); HLOAD(6, "384"); HLOAD(7, "448");
            #undef HLOAD
            asm volatile("s_waitcnt vmcnt(0)"
                : "+v"(hv[0]), "+v"(hv[1]), "+v"(hv[2]), "+v"(hv[3]),
                  "+v"(hv[4]), "+v"(hv[5]), "+v"(hv[6]), "+v"(hv[7]));
            #pragma unroll
            for (int kc = 0; kc < 8; ++kc) {
                union { int4v i; short8 s; } u; u.i = hv[kc];
                #pragma unroll
                for (int nt = 0; nt < 8; ++nt)
                    acc[nt] = __builtin_amdgcn_mfma_f32_16x16x32_bf16(
                        u.s, bfrag[kc][nt], acc[nt], 0, 0, 0);
            }
        }

        // K-partials to LDS (C layout: row = quad*4+r, col = nt*16+l15)
        #pragma unroll
        for (int nt = 0; nt < 8; ++nt) {
            const int col = nt * 16 + l15;
            #pragma unroll
            for (int r = 0; r < 4; ++r)
                P[wv][quad * 4 + r][col] = acc[nt][r];
        }
        __syncthreads();

        // elementwise: thread -> (row r_ew, h-cols jj_ew, jj_ew+1)
        {
            float h2[2];
            #pragma unroll
            for (int e = 0; e < 2; ++e) {
                const int jj = jj_ew + e;
                const int r  = r_ew;
                float gi = biasLds[jj]      + P[0][r][jj]      + P[1][r][jj]      + P[2][r][jj]      + P[3][r][jj];
                float gf = biasLds[32 + jj] + P[0][r][32 + jj] + P[1][r][32 + jj] + P[2][r][32 + jj] + P[3][r][32 + jj];
                float go = biasLds[64 + jj] + P[0][r][64 + jj] + P[1][r][64 + jj] + P[2][r][64 + jj] + P[3][r][64 + jj];
                float gz = biasLds[96 + jj] + P[0][r][96 + jj] + P[1][r][96 + jj] + P[2][r][96 + jj] + P[3][r][96 + jj];
                const float c_old = cst[r][jj];
                const float cn = sigm(gi) * tanh_fast(gz) + sigm(gf) * c_old;
                const float hn = sigm(go) * tanh_fast(cn);
                cst[r][jj]  = cn;
                csum[r][jj] += cn;
                hsum[r][jj] += hn;
                h2[e] = hn;
            }
            const unsigned pk = (unsigned)f2bf(h2[0]) | ((unsigned)f2bf(h2[1]) << 16);
            unsigned* dst = (unsigned*)(hW + (size_t)(rb + r_ew) * HHH + jbase + jj_ew);
            __hip_atomic_store(dst, pk, __ATOMIC_RELAXED, __HIP_MEMORY_SCOPE_AGENT);  // sc1 -> LLC
        }

        // per-wave publish: drain own h-stores (LLC ack), lane0 stores slot.
        asm volatile("s_waitcnt vmcnt(0)" ::: "memory");
        if (lane == 0)
            __hip_atomic_store(slots + (wc * 4 + wv), (unsigned)(t + 1),
                               __ATOMIC_RELAXED, __HIP_MEMORY_SCOPE_AGENT);

        __syncthreads();   // protect P for next iteration's writes
    }

    // global final barrier: wave wv checks group wv's 64 slots.
    {
        unsigned* base = sync + wv * 64 + lane;
        for (;;) {
            unsigned v = __hip_atomic_load(base, __ATOMIC_RELAXED, __HIP_MEMORY_SCOPE_AGENT);
            if (__all((int)(v >= (unsigned)TSTEPS))) break;
        }
    }
    __syncthreads();

    const float invT = 1.0f / (float)TSTEPS;
    {
        const int b = rb + r_ew;
        const size_t o0 = (size_t)b * HHH + jbase + jj_ew;
        out[o0]                              = hsum[r_ew][jj_ew] * invT;
        out[o0 + 1]                          = hsum[r_ew][jj_ew + 1] * invT;
        out[(size_t)(BATCH * HHH) + o0]      = csum[r_ew][jj_ew] * invT;
        out[(size_t)(BATCH * HHH) + o0 + 1]  = csum[r_ew][jj_ew + 1] * invT;
    }
}

extern "C" void kernel_launch(void* const* d_in, const int* in_sizes, int n_in,
                              void* d_out, int out_size, void* d_ws, size_t ws_size,
                              hipStream_t stream) {
    (void)in_sizes; (void)n_in; (void)out_size;
    const float* X  = (const float*)d_in[0];
    const float* Wx = (const float*)d_in[1];
    const float* bx = (const float*)d_in[2];
    const float* Wh = (const float*)d_in[3];
    const float* bh = (const float*)d_in[4];
    float* out = (float*)d_out;

    const size_t HBUF_BYTES = (size_t)2 * BATCH * HHH * 2;   // 128 KiB
    const size_t SYNC_BYTES = 4096;                          // 4 groups x 256B slot lines
    char* scratch = (ws_size >= HBUF_BYTES + SYNC_BYTES) ? (char*)d_ws : (char*)d_out;
    unsigned short* hbuf = (unsigned short*)scratch;
    unsigned* sync = (unsigned*)(scratch + HBUF_BYTES);

    hipMemsetAsync(scratch, 0, HBUF_BYTES + SYNC_BYTES, stream);
    lstm_scan<<<GB * GC, NTHR, 0, stream>>>(X, Wx, bx, Wh, bh, out, hbuf, sync);
}